// Round 12
// baseline (265.680 us; speedup 1.0000x reference)
//
#include <hip/hip_runtime.h>
#include <hip/hip_bf16.h>
#include <stdint.h>

// CrossAttention: out = softmax((x@Wq)(ctx@Wk)^T * scale) @ (ctx@Wv) @ Wo + bo
// B=16, NQ=4096, NK=77, QD=512, CD=768, H=8, DH=64, INNER=512
//
// Round 12: qproj2 (BK=32, 16 barriers -> 2x per-step stall overhead) replaced
// by qproj3: gemm2/m97 skeleton at BK=64, SINGLE-buffered (48 KB, 3 blk/CU),
// A staged as f32 via linear GLDS, cvt_pk at fragment read. 8 barriers.
// Everything else identical to round 11.

typedef __attribute__((ext_vector_type(8))) short bf16x8;
typedef __attribute__((ext_vector_type(4))) float f32x4;
typedef __attribute__((ext_vector_type(4))) short short4v;
typedef __attribute__((ext_vector_type(4))) float float4v;
typedef __attribute__((ext_vector_type(2))) unsigned uint2v;
typedef __attribute__((ext_vector_type(4))) unsigned uint4v;

#define DEVINL __device__ __forceinline__

DEVINL short f2bf(float f) {
  unsigned u = __builtin_bit_cast(unsigned, f);
  unsigned r = (u + 0x7FFFu + ((u >> 16) & 1u)) >> 16;  // RNE
  return (short)(unsigned short)r;
}

// packed f32x2 -> bf16x2 (RTNE), single VALU op
DEVINL unsigned pkbf(float lo, float hi) {
  unsigned r;
  asm("v_cvt_pk_bf16_f32 %0, %1, %2" : "=v"(r) : "v"(lo), "v"(hi));
  return r;
}

#define GLDS16(gp, sp)                                                \
  __builtin_amdgcn_global_load_lds(                                   \
      (const __attribute__((address_space(1))) void*)(gp),            \
      (__attribute__((address_space(3))) void*)(sp), 16, 0, 0)

// ---------------- zero fill (float4 granules) ------------------------------
__global__ __launch_bounds__(256) void fill0(float4v* __restrict__ p, int n4) {
  int i = blockIdx.x * 256 + threadIdx.x;
  if (i < n4) p[i] = float4v{0.f, 0.f, 0.f, 0.f};
}

// ---------------- weight transpose+convert: W[K][N] f32 -> Wt[N][K] bf16 ----
__global__ __launch_bounds__(256) void wt_conv(const float* __restrict__ W,
                                               short* __restrict__ Wt,
                                               int K, int N) {
  __shared__ short Tl[64][65];
  const int kt = blockIdx.y * 64, nt = blockIdx.x * 64;
#pragma unroll
  for (int i = 0; i < 16; ++i) {
    int idx = threadIdx.x + i * 256;
    int r = idx >> 6, c = idx & 63;
    Tl[c][r] = f2bf(W[(size_t)(kt + r) * N + nt + c]);
  }
  __syncthreads();
#pragma unroll
  for (int i = 0; i < 16; ++i) {
    int idx = threadIdx.x + i * 256;
    int r = idx >> 6, c = idx & 63;
    Wt[(size_t)(nt + r) * K + kt + c] = Tl[r][c];
  }
}

// ---------------- O-proj: 2-phase dbuf GEMM, bf16 A/B ----------------------
// C[M][512] f32+bias = A[M][512]bf16 @ Bt[512][512]bf16^T. 128x128 tile,
// BK=64, 4 waves, 1-D grid %8==0, XCD swizzle.
__global__ __launch_bounds__(256) void gemm2(const short* __restrict__ A,
                                             const short* __restrict__ Bt,
                                             float* __restrict__ C,
                                             const float* __restrict__ bias) {
  __shared__ short As[2][128 * 64];
  __shared__ short Bs[2][128 * 64];

  const int tid = threadIdx.x;
  const int lane = tid & 63, w = tid >> 6;
  const int wm = w >> 1, wn = w & 1;
  const int quad = lane >> 4, l16 = lane & 15;

  const int cpx = gridDim.x >> 3;
  const int swz = (blockIdx.x & 7) * cpx + (blockIdx.x >> 3);
  const int m0 = (swz >> 2) * 128, n0 = (swz & 3) * 128;

  const int lr = lane >> 3, lc = (lane & 7) * 8;

  f32x4 acc[4][4] = {};

  // prologue: stage tile 0
#pragma unroll
  for (int p = 0; p < 4; ++p) {
    const int rowb = w * 32 + p * 8;
    GLDS16(A + (size_t)(m0 + rowb + lr) * 512 + lc, &As[0][rowb * 64]);
    GLDS16(Bt + (size_t)(n0 + rowb + lr) * 512 + lc, &Bs[0][rowb * 64]);
  }
  __syncthreads();

  for (int t = 0; t < 8; ++t) {
    const int cur = t & 1;
    if (t < 7) {
      const int k1 = (t + 1) * 64;
#pragma unroll
      for (int p = 0; p < 4; ++p) {
        const int rowb = w * 32 + p * 8;
        GLDS16(A + (size_t)(m0 + rowb + lr) * 512 + k1 + lc,
               &As[cur ^ 1][rowb * 64]);
        GLDS16(Bt + (size_t)(n0 + rowb + lr) * 512 + k1 + lc,
               &Bs[cur ^ 1][rowb * 64]);
      }
    }
#pragma unroll
    for (int ks = 0; ks < 2; ++ks) {
      bf16x8 af[4], bfr[4];
#pragma unroll
      for (int m = 0; m < 4; ++m)
        af[m] = *(bf16x8*)&As[cur][(wm * 64 + m * 16 + l16) * 64 + ks * 32 + quad * 8];
#pragma unroll
      for (int n = 0; n < 4; ++n)
        bfr[n] = *(bf16x8*)&Bs[cur][(wn * 64 + n * 16 + l16) * 64 + ks * 32 + quad * 8];
#pragma unroll
      for (int m = 0; m < 4; ++m)
#pragma unroll
        for (int n = 0; n < 4; ++n)
          acc[m][n] = __builtin_amdgcn_mfma_f32_16x16x32_bf16(af[m], bfr[n],
                                                              acc[m][n], 0, 0, 0);
    }
    if (t < 7) __syncthreads();
  }

#pragma unroll
  for (int m = 0; m < 4; ++m)
#pragma unroll
    for (int n = 0; n < 4; ++n) {
      const int col = n0 + wn * 64 + n * 16 + l16;
      const int rowb = m0 + wm * 64 + m * 16 + quad * 4;
      const float badd = bias[col];
#pragma unroll
      for (int r = 0; r < 4; ++r)
        C[(size_t)(rowb + r) * 512 + col] = acc[m][n][r] + badd;
    }
}

// ---------------- Q-proj: m97 skeleton, f32 A via linear GLDS, BK=64 --------
// C[M][512] bf16 = A[M][512]f32 @ Bt[512][512]bf16^T. 128x128 tile, 8 steps,
// single-buffered: As f32 32 KB + Bs bf16 16 KB = 48 KB (3 blocks/CU).
__global__ __launch_bounds__(256) void qproj3(const float* __restrict__ A,
                                              const short* __restrict__ Bt,
                                              short* __restrict__ C) {
  __shared__ float As[128 * 64];  // 32 KB linear (GLDS)
  __shared__ short Bs[128 * 64];  // 16 KB linear (GLDS)

  const int tid = threadIdx.x;
  const int lane = tid & 63, w = tid >> 6;
  const int wm = w >> 1, wn = w & 1;
  const int quad = lane >> 4, l16 = lane & 15;

  const int cpx = gridDim.x >> 3;
  const int swz = (blockIdx.x & 7) * cpx + (blockIdx.x >> 3);
  const int m0 = (swz >> 2) * 128, n0 = (swz & 3) * 128;

  // A chunk (1 KB = 4 rows x 64 f32): lane -> row lane>>4, col (lane&15)*4
  const int alr = lane >> 4, alc = (lane & 15) * 4;
  // B chunk (1 KB = 8 rows x 64 bf16): lane -> row lane>>3, col (lane&7)*8
  const int blr = lane >> 3, blc = (lane & 7) * 8;

  f32x4 acc[4][4] = {};

  for (int k0 = 0; k0 < 512; k0 += 64) {
    // A tile [128][64] f32: 32 chunks, 8 per wave
#pragma unroll
    for (int p = 0; p < 8; ++p) {
      const int rowb = w * 32 + p * 4;
      GLDS16(A + (size_t)(m0 + rowb + alr) * 512 + k0 + alc, &As[rowb * 64]);
    }
    // B tile [128][64] bf16: 16 chunks, 4 per wave
#pragma unroll
    for (int p = 0; p < 4; ++p) {
      const int rowb = w * 32 + p * 8;
      GLDS16(Bt + (size_t)(n0 + rowb + blr) * 512 + k0 + blc, &Bs[rowb * 64]);
    }
    __syncthreads();

#pragma unroll
    for (int ks = 0; ks < 2; ++ks) {
      bf16x8 af[4], bfr[4];
#pragma unroll
      for (int m = 0; m < 4; ++m) {
        const float* ap = &As[(wm * 64 + m * 16 + l16) * 64 + ks * 32 + quad * 8];
        float4v a0 = *(const float4v*)ap;
        float4v a1 = *(const float4v*)(ap + 4);
        uint4v u = {pkbf(a0[0], a0[1]), pkbf(a0[2], a0[3]),
                    pkbf(a1[0], a1[1]), pkbf(a1[2], a1[3])};
        af[m] = __builtin_bit_cast(bf16x8, u);
      }
#pragma unroll
      for (int n = 0; n < 4; ++n)
        bfr[n] = *(bf16x8*)&Bs[(wn * 64 + n * 16 + l16) * 64 + ks * 32 + quad * 8];
#pragma unroll
      for (int m = 0; m < 4; ++m)
#pragma unroll
        for (int n = 0; n < 4; ++n)
          acc[m][n] = __builtin_amdgcn_mfma_f32_16x16x32_bf16(af[m], bfr[n],
                                                              acc[m][n], 0, 0, 0);
    }
    __syncthreads();
  }

#pragma unroll
  for (int m = 0; m < 4; ++m)
#pragma unroll
    for (int n = 0; n < 4; ++n) {
      const int col = n0 + wn * 64 + n * 16 + l16;
      const int rowb = m0 + wm * 64 + m * 16 + quad * 4;
#pragma unroll
      for (int r = 0; r < 4; ++r)
        C[(size_t)(rowb + r) * 512 + col] = f2bf(acc[m][n][r]);
    }
}

// ---------------- small GEMM (f32 A): C = A[M][K]f32 @ Bt[512][K]^T ---------
// TRANS=0: bf16 C[M][512].  TRANS=1: scatter to Vtg[((b*8+h)*64+d)*104+key].
template <int TRANS>
__global__ __launch_bounds__(256) void gemm_small(const float* __restrict__ A,
                                                  const short* __restrict__ Bt,
                                                  short* __restrict__ C,
                                                  int M, int K) {
  __shared__ short Al[32][40];
  __shared__ short Bl[128][40];

  const int tid = threadIdx.x;
  const int lane = tid & 63, wid = tid >> 6;
  const int wm = wid >> 1, wn = wid & 1;
  const int quad = lane >> 4, l16 = lane & 15;
  const int m0 = blockIdx.y * 32, n0 = blockIdx.x * 128;

  f32x4 acc[4] = {};

  for (int k0 = 0; k0 < K; k0 += 32) {
    for (int idx = tid; idx < 32 * 8; idx += 256) {
      int row = idx >> 3, kq = idx & 7;
      float4v v = {};
      if (m0 + row < M)
        v = *(const float4v*)(A + (size_t)(m0 + row) * K + k0 + kq * 4);
      short4v s = {f2bf(v[0]), f2bf(v[1]), f2bf(v[2]), f2bf(v[3])};
      *(short4v*)&Al[row][kq * 4] = s;
    }
    for (int idx = tid; idx < 512; idx += 256) {
      int row = idx >> 2, kq = idx & 3;
      *(bf16x8*)&Bl[row][kq * 8] =
          *(const bf16x8*)(Bt + (size_t)(n0 + row) * K + k0 + kq * 8);
    }
    __syncthreads();

    bf16x8 a = *(bf16x8*)&Al[wm * 16 + l16][quad * 8];
#pragma unroll
    for (int n = 0; n < 4; ++n) {
      bf16x8 b = *(bf16x8*)&Bl[wn * 64 + n * 16 + l16][quad * 8];
      acc[n] = __builtin_amdgcn_mfma_f32_16x16x32_bf16(a, b, acc[n], 0, 0, 0);
    }
    __syncthreads();
  }

#pragma unroll
  for (int n = 0; n < 4; ++n) {
    const int col = n0 + wn * 64 + n * 16 + l16;
    const int rowb = m0 + wm * 16 + quad * 4;
#pragma unroll
    for (int r = 0; r < 4; ++r) {
      const int rr = rowb + r;
      if (rr < M) {
        if constexpr (TRANS == 0) {
          C[(size_t)rr * 512 + col] = f2bf(acc[n][r]);
        } else {
          const int bb = rr / 77, key = rr - bb * 77;
          C[(size_t)((bb * 8 + (col >> 6)) * 64 + (col & 63)) * 104 + key] =
              f2bf(acc[n][r]);
        }
      }
    }
  }
}

// ---------------- standalone attention -------------------------------------
// 512 thr (8 waves), block = (qtile of 128 rows, head, batch). Each wave owns
// 16 q-rows; Q from global; K [80][72] LDS; V^T [64][104] GLDS; P per-wave
// (no QK->PV barrier). Exactly ONE __syncthreads per block.
__global__ __launch_bounds__(512) void attn3(const short* __restrict__ Qb,
                                             const short* __restrict__ Kb,
                                             const short* __restrict__ Vtg,
                                             short* __restrict__ AOb) {
  __shared__ short Kl[80 * 72];       // 11520 B (rows 77..79 uninit, masked)
  __shared__ short Vt[64 * 104];      // 13312 B
  __shared__ short Pw[8 * 16 * 104];  // 26624 B

  const int tid = threadIdx.x;
  const int lane = tid & 63, w = tid >> 6;
  const int quad = lane >> 4, l16 = lane & 15;
  const int qt = blockIdx.x, h = blockIdx.y, b = blockIdx.z;
  const size_t kbase = ((size_t)b * 77) * 512 + h * 64;

  // stage K rows 0..76 (8 b128 per row)
  for (int idx = tid; idx < 616; idx += 512) {
    const int r = idx >> 3, c = (idx & 7) * 8;
    *(bf16x8*)&Kl[r * 72 + c] =
        *(const bf16x8*)(Kb + kbase + (size_t)r * 512 + c);
  }
  // stage V^T linearly via GLDS (13 chunks of 1 KB)
  for (int cid = w; cid < 13; cid += 8)
    GLDS16(Vtg + (size_t)(b * 8 + h) * 6656 + cid * 512 + lane * 8,
           &Vt[cid * 512]);
  __syncthreads();

  const size_t qrow = (size_t)b * 4096 + qt * 128 + w * 16 + l16;
  const short* qp = Qb + qrow * 512 + h * 64;

  // Q fragment (B operand of sim^T = K . Q^T): col=q=l16, k=d
  bf16x8 qfr[2];
#pragma unroll
  for (int ks = 0; ks < 2; ++ks)
    qfr[ks] = *(const bf16x8*)(qp + ks * 32 + quad * 8);

  // sim^T: 5 frags of 16 keys x 16 q
  f32x4 c[5] = {};
#pragma unroll
  for (int f = 0; f < 5; ++f)
#pragma unroll
    for (int ks = 0; ks < 2; ++ks) {
      bf16x8 a = *(bf16x8*)&Kl[(f * 16 + l16) * 72 + ks * 32 + quad * 8];
      c[f] = __builtin_amdgcn_mfma_f32_16x16x32_bf16(a, qfr[ks], c[f], 0, 0, 0);
    }

  // scale + mask + softmax over keys
  float mx = -1e30f;
#pragma unroll
  for (int f = 0; f < 5; ++f)
#pragma unroll
    for (int r = 0; r < 4; ++r) {
      const int key = f * 16 + quad * 4 + r;
      float v = c[f][r] * 0.125f;
      v = (key < 77) ? v : -1e30f;
      c[f][r] = v;
      mx = fmaxf(mx, v);
    }
  mx = fmaxf(mx, __shfl_xor(mx, 16));
  mx = fmaxf(mx, __shfl_xor(mx, 32));

  short* pbase = Pw + (w * 16 + l16) * 104;
  float sum = 0.f;
#pragma unroll
  for (int f = 0; f < 5; ++f) {
    float e0 = __expf(c[f][0] - mx), e1 = __expf(c[f][1] - mx);
    float e2 = __expf(c[f][2] - mx), e3 = __expf(c[f][3] - mx);
    sum += (e0 + e1) + (e2 + e3);
    uint2v sv2 = {pkbf(e0, e1), pkbf(e2, e3)};
    *(uint2v*)(pbase + f * 16 + quad * 4) = sv2;
  }
  sum += __shfl_xor(sum, 16);
  sum += __shfl_xor(sum, 32);
  const float inv = 1.0f / sum;

  // P fragments: keys 0..63 from LDS; keys 64..79 for quad<2; 80..95 zero.
  bf16x8 pb0 = *(bf16x8*)(pbase + quad * 8);
  bf16x8 pb1 = *(bf16x8*)(pbase + 32 + quad * 8);
  bf16x8 pb2 = bf16x8{0, 0, 0, 0, 0, 0, 0, 0};
  if (quad < 2) pb2 = *(bf16x8*)(pbase + 64 + quad * 8);

  // out^T = V^T . P^T
  f32x4 o[4] = {};
#pragma unroll
  for (int mt = 0; mt < 4; ++mt) {
    const short* vrow = &Vt[(mt * 16 + l16) * 104];
    o[mt] = __builtin_amdgcn_mfma_f32_16x16x32_bf16(
        *(bf16x8*)(vrow + quad * 8), pb0, o[mt], 0, 0, 0);
    o[mt] = __builtin_amdgcn_mfma_f32_16x16x32_bf16(
        *(bf16x8*)(vrow + 32 + quad * 8), pb1, o[mt], 0, 0, 0);
    o[mt] = __builtin_amdgcn_mfma_f32_16x16x32_bf16(
        *(bf16x8*)(vrow + 64 + quad * 8), pb2, o[mt], 0, 0, 0);
  }

  short* op = AOb + qrow * 512 + h * 64;
#pragma unroll
  for (int mt = 0; mt < 4; ++mt) {
    uint2v sv2 = {pkbf(o[mt][0] * inv, o[mt][1] * inv),
                  pkbf(o[mt][2] * inv, o[mt][3] * inv)};
    *(uint2v*)(op + mt * 16 + quad * 4) = sv2;
  }
}

extern "C" void kernel_launch(void* const* d_in, const int* in_sizes, int n_in,
                              void* d_out, int out_size, void* d_ws, size_t ws_size,
                              hipStream_t stream) {
  const float* x   = (const float*)d_in[0];
  const float* ctx = (const float*)d_in[1];
  const float* Wq  = (const float*)d_in[2];
  const float* Wk  = (const float*)d_in[3];
  const float* Wv  = (const float*)d_in[4];
  const float* Wo  = (const float*)d_in[5];
  const float* bo  = (const float*)d_in[6];
  float* out = (float*)d_out;

  char* ws = (char*)d_ws;
  size_t off = 0;
  short* wqt = (short*)(ws + off); off += 512 * 512 * 2;
  short* wkt = (short*)(ws + off); off += 768 * 512 * 2;
  short* wvt = (short*)(ws + off); off += 768 * 512 * 2;
  short* wot = (short*)(ws + off); off += 512 * 512 * 2;
  short* Kb  = (short*)(ws + off); off += 1232 * 512 * 2;
  short* Vtg = (short*)(ws + off); off += (size_t)16 * 8 * 64 * 104 * 2;
  short* Qb  = (short*)(ws + off); off += (size_t)65536 * 512 * 2;
  short* AOb = (short*)(ws + off); off += (size_t)65536 * 512 * 2;

  // weights -> bf16 transposed [N][K]
  wt_conv<<<dim3(8, 8), 256, 0, stream>>>(Wq, wqt, 512, 512);
  wt_conv<<<dim3(8, 12), 256, 0, stream>>>(Wk, wkt, 768, 512);
  wt_conv<<<dim3(8, 12), 256, 0, stream>>>(Wv, wvt, 768, 512);
  wt_conv<<<dim3(8, 8), 256, 0, stream>>>(Wo, wot, 512, 512);

  // zero-fill Vtg pads (16*8*64*104*2 B / 16 = 106496 float4)
  fill0<<<416, 256, 0, stream>>>((float4v*)Vtg, 106496);
  gemm_small<0><<<dim3(4, 39), 256, 0, stream>>>(ctx, wkt, Kb, 1232, 768);
  gemm_small<1><<<dim3(4, 39), 256, 0, stream>>>(ctx, wvt, Vtg, 1232, 768);

  // Q projection (f32 A, BK=64 single-buffer) -> Qb bf16
  qproj3<<<2048, 256, 0, stream>>>(x, wqt, Qb);

  // standalone attention -> AOb bf16
  attn3<<<dim3(32, 8, 16), 512, 0, stream>>>(Qb, Kb, Vtg, AOb);

  // output projection + bias (2-phase dbuf) -> f32 d_out
  gemm2<<<2048, 256, 0, stream>>>(AOb, wot, out, bo);
}

// Round 13
// 187.253 us; speedup vs baseline: 1.4188x; 1.4188x over previous
//
#include <hip/hip_runtime.h>
#include <hip/hip_bf16.h>
#include <stdint.h>

// CrossAttention: out = softmax((x@Wq)(ctx@Wk)^T * scale) @ (ctx@Wv) @ Wo + bo
// B=16, NQ=4096, NK=77, QD=512, CD=768, H=8, DH=64, INNER=512
//
// Round 13: consolidation. Ledger audit showed the round-10 un-fuse was net
// negative (fused qattn 110 < qproj 120 + attn3 28). Revert to round-9 qattn
// (proven), keep round-12 gemm2 (proven), and collapse 7 prep dispatches
// into 2 batched kernels (prep_all: 4x wt_conv + Vtg fill; kvproj: K+V).

typedef __attribute__((ext_vector_type(8))) short bf16x8;
typedef __attribute__((ext_vector_type(4))) float f32x4;
typedef __attribute__((ext_vector_type(4))) short short4v;
typedef __attribute__((ext_vector_type(4))) float float4v;
typedef __attribute__((ext_vector_type(2))) unsigned uint2v;
typedef __attribute__((ext_vector_type(4))) unsigned uint4v;

#define DEVINL __device__ __forceinline__

DEVINL short f2bf(float f) {
  unsigned u = __builtin_bit_cast(unsigned, f);
  unsigned r = (u + 0x7FFFu + ((u >> 16) & 1u)) >> 16;  // RNE
  return (short)(unsigned short)r;
}

// packed f32x2 -> bf16x2 (RTNE), single VALU op
DEVINL unsigned pkbf(float lo, float hi) {
  unsigned r;
  asm("v_cvt_pk_bf16_f32 %0, %1, %2" : "=v"(r) : "v"(lo), "v"(hi));
  return r;
}

#define GLDS16(gp, sp)                                                \
  __builtin_amdgcn_global_load_lds(                                   \
      (const __attribute__((address_space(1))) void*)(gp),            \
      (__attribute__((address_space(3))) void*)(sp), 16, 0, 0)

// ---------------- batched prep: 4x weight transpose + Vtg zero-fill --------
// grid (8, 12, 5). z=0..3: W[K][512] f32 -> Wt[512][K] bf16 (kt guard).
// z=4: zero-fill Vtg (12288 float4 granules).
__global__ __launch_bounds__(256) void prep_all(
    const float* __restrict__ Wq, const float* __restrict__ Wk,
    const float* __restrict__ Wv, const float* __restrict__ Wo,
    short* __restrict__ wqt, short* __restrict__ wkt,
    short* __restrict__ wvt, short* __restrict__ wot,
    float4v* __restrict__ vfill) {
  const int z = blockIdx.z;
  if (z == 4) {
    const int i = (blockIdx.y * 8 + blockIdx.x) * 256 + threadIdx.x;
    if (i < 12288) vfill[i] = float4v{0.f, 0.f, 0.f, 0.f};
    return;
  }
  const float* W;
  short* Wt;
  int K;
  switch (z) {
    case 0: W = Wq; Wt = wqt; K = 512; break;
    case 1: W = Wk; Wt = wkt; K = 768; break;
    case 2: W = Wv; Wt = wvt; K = 768; break;
    default: W = Wo; Wt = wot; K = 512; break;
  }
  const int kt = blockIdx.y * 64;
  if (kt >= K) return;
  const int nt = blockIdx.x * 64;

  __shared__ short Tl[64][65];
#pragma unroll
  for (int i = 0; i < 16; ++i) {
    int idx = threadIdx.x + i * 256;
    int r = idx >> 6, c = idx & 63;
    Tl[c][r] = f2bf(W[(size_t)(kt + r) * 512 + nt + c]);
  }
  __syncthreads();
#pragma unroll
  for (int i = 0; i < 16; ++i) {
    int idx = threadIdx.x + i * 256;
    int r = idx >> 6, c = idx & 63;
    Wt[(size_t)(nt + r) * K + kt + c] = Tl[r][c];
  }
}

// ---------------- K+V projections in one dispatch ---------------------------
// grid (4, 39, 2). z=0: Kb[M][512] bf16 = ctx @ wkt^T.
// z=1: V scatter -> Vtg[((b*8+h)*64+d)*96 + key] (pads pre-zeroed).
__global__ __launch_bounds__(256) void kvproj(const float* __restrict__ A,
                                              const short* __restrict__ wkt,
                                              const short* __restrict__ wvt,
                                              short* __restrict__ Kb,
                                              short* __restrict__ Vtg) {
  __shared__ short Al[32][40];
  __shared__ short Bl[128][40];

  const int TRANS = blockIdx.z;
  const short* Bt = TRANS ? wvt : wkt;

  const int tid = threadIdx.x;
  const int lane = tid & 63, wid = tid >> 6;
  const int wm = wid >> 1, wn = wid & 1;
  const int quad = lane >> 4, l16 = lane & 15;
  const int m0 = blockIdx.y * 32, n0 = blockIdx.x * 128;
  const int M = 1232, K = 768;

  f32x4 acc[4] = {};

  for (int k0 = 0; k0 < K; k0 += 32) {
    for (int idx = tid; idx < 32 * 8; idx += 256) {
      int row = idx >> 3, kq = idx & 7;
      float4v v = {};
      if (m0 + row < M)
        v = *(const float4v*)(A + (size_t)(m0 + row) * K + k0 + kq * 4);
      short4v s = {f2bf(v[0]), f2bf(v[1]), f2bf(v[2]), f2bf(v[3])};
      *(short4v*)&Al[row][kq * 4] = s;
    }
    for (int idx = tid; idx < 512; idx += 256) {
      int row = idx >> 2, kq = idx & 3;
      *(bf16x8*)&Bl[row][kq * 8] =
          *(const bf16x8*)(Bt + (size_t)(n0 + row) * K + k0 + kq * 8);
    }
    __syncthreads();

    bf16x8 a = *(bf16x8*)&Al[wm * 16 + l16][quad * 8];
#pragma unroll
    for (int n = 0; n < 4; ++n) {
      bf16x8 b = *(bf16x8*)&Bl[wn * 64 + n * 16 + l16][quad * 8];
      acc[n] = __builtin_amdgcn_mfma_f32_16x16x32_bf16(a, b, acc[n], 0, 0, 0);
    }
    __syncthreads();
  }

#pragma unroll
  for (int n = 0; n < 4; ++n) {
    const int col = n0 + wn * 64 + n * 16 + l16;
    const int rowb = m0 + wm * 16 + quad * 4;
#pragma unroll
    for (int r = 0; r < 4; ++r) {
      const int rr = rowb + r;
      if (rr < M) {
        if (!TRANS) {
          Kb[(size_t)rr * 512 + col] = f2bf(acc[n][r]);
        } else {
          const int bb = rr / 77, key = rr - bb * 77;
          Vtg[(size_t)((bb * 8 + (col >> 6)) * 64 + (col & 63)) * 96 + key] =
              f2bf(acc[n][r]);
        }
      }
    }
  }
}

// ---------------- fused Q-proj + attention (round-9 proven) -----------------
// 1024 thr (16 waves). Phase 1: BK=32, 16 steps, LDS double-buffer
// (xb[2][128][40], wsW[2][512][40]), reg-staged, prefetch after barrier,
// ONE __syncthreads per step. Phase 2: 4 iters x 2 heads.
__global__ __launch_bounds__(1024, 4) void qattn(const float* __restrict__ x,
                                                 const short* __restrict__ wqt,
                                                 const short* __restrict__ Kb,
                                                 const short* __restrict__ Vtg,
                                                 short* __restrict__ AOb) {
  __shared__ __align__(16) char smem[125440];
  short* xb  = (short*)smem;               // ph1: [2][128][40] bf16, 20480 B
  short* wsW = (short*)(smem + 20480);     // ph1: [2][512][40] bf16, 81920 B
  short* Qh  = (short*)smem;               // ph2: [2][128][72], 36864 B
  short* Kl  = (short*)(smem + 36864);     // ph2: [2][80][72], 23040 B
  short* Vt  = (short*)(smem + 59904);     // ph2: [2][64][96], 24576 B
  short* Pw  = (short*)(smem + 84480);     // ph2: [16][16][80], 40960 B

  const int tid = threadIdx.x;
  const int lane = tid & 63, w = tid >> 6;
  const int wm = w >> 3, wn = w & 7;
  const int quad = lane >> 4, l16 = lane & 15;
  const int m0 = blockIdx.x * 128;
  const int b = m0 >> 12;

  f32x4 acc[4][4] = {};

  // ============ phase 1: Q projection, BK=32 pipelined (16 steps) ==========
  const int xrow = tid >> 3, xcol = (tid & 7) * 4;
  const int wr0 = tid >> 2, wc0 = (tid & 3) * 8;
  const int wr1 = (tid + 1024) >> 2, wc1 = wc0;

  const float* xg = x + (size_t)(m0 + xrow) * 512 + xcol;
  const short* wg0 = wqt + (size_t)wr0 * 512 + wc0;
  const short* wg1 = wqt + (size_t)wr1 * 512 + wc1;

  float4v px;
  bf16x8 pw0, pw1;
  px = *(const float4v*)(xg);
  pw0 = *(const bf16x8*)(wg0);
  pw1 = *(const bf16x8*)(wg1);

  for (int t = 0; t < 16; ++t) {
    short* xbuf = xb + (t & 1) * 5120;
    short* wbuf = wsW + (t & 1) * 20480;

    *(uint2v*)&xbuf[xrow * 40 + xcol] =
        uint2v{pkbf(px[0], px[1]), pkbf(px[2], px[3])};
    *(bf16x8*)&wbuf[wr0 * 40 + wc0] = pw0;
    *(bf16x8*)&wbuf[wr1 * 40 + wc1] = pw1;

    __syncthreads();

    if (t < 15) {
      const int k1 = (t + 1) * 32;
      px = *(const float4v*)(xg + k1);
      pw0 = *(const bf16x8*)(wg0 + k1);
      pw1 = *(const bf16x8*)(wg1 + k1);
    }

    bf16x8 af[4], bfr[4];
#pragma unroll
    for (int m = 0; m < 4; ++m)
      af[m] = *(bf16x8*)&xbuf[(wm * 64 + m * 16 + l16) * 40 + quad * 8];
#pragma unroll
    for (int n = 0; n < 4; ++n)
      bfr[n] = *(bf16x8*)&wbuf[(wn * 64 + n * 16 + l16) * 40 + quad * 8];
#pragma unroll
    for (int m = 0; m < 4; ++m)
#pragma unroll
      for (int n = 0; n < 4; ++n)
        acc[m][n] = __builtin_amdgcn_mfma_f32_16x16x32_bf16(af[m], bfr[n],
                                                            acc[m][n], 0, 0, 0);
  }
  __syncthreads();

  // ================= phase 2: 4 iters x 2 heads =================
#pragma unroll
  for (int it = 0; it < 4; ++it) {
    if (it) __syncthreads();

    if ((wn >> 1) == it) {
      const int slot = wn & 1;
#pragma unroll
      for (int m = 0; m < 4; ++m)
#pragma unroll
        for (int n = 0; n < 4; ++n)
#pragma unroll
          for (int r = 0; r < 4; ++r)
            Qh[slot * 9216 + (wm * 64 + m * 16 + quad * 4 + r) * 72 +
               n * 16 + l16] = f2bf(acc[m][n][r]);
    }
    for (int idx = tid; idx < 1232; idx += 1024) {
      const int sk = idx >= 616;
      const int e = idx - sk * 616;
      const int r = e >> 3, cc = (e & 7) * 8;
      *(bf16x8*)&Kl[sk * 5760 + r * 72 + cc] =
          *(const bf16x8*)(Kb + ((size_t)b * 77 + r) * 512 +
                           (it * 2 + sk) * 64 + cc);
    }
    for (int cid = w; cid < 24; cid += 16) {
      const int sv = cid >= 12;
      const int c12 = cid - sv * 12;
      GLDS16(Vtg + (size_t)(b * 8 + it * 2 + sv) * 6144 + c12 * 512 + lane * 8,
             Vt + sv * 6144 + c12 * 512);
    }
    __syncthreads();

    bf16x8 qfr[2];
#pragma unroll
    for (int ks = 0; ks < 2; ++ks)
      qfr[ks] = *(bf16x8*)&Qh[wm * 9216 + (wn * 16 + l16) * 72 +
                              ks * 32 + quad * 8];

    f32x4 c[5] = {};
#pragma unroll
    for (int f = 0; f < 5; ++f)
#pragma unroll
      for (int ks = 0; ks < 2; ++ks) {
        bf16x8 a = *(bf16x8*)&Kl[wm * 5760 + (f * 16 + l16) * 72 +
                                 ks * 32 + quad * 8];
        c[f] = __builtin_amdgcn_mfma_f32_16x16x32_bf16(a, qfr[ks], c[f], 0, 0, 0);
      }

    float mx = -1e30f;
#pragma unroll
    for (int f = 0; f < 5; ++f)
#pragma unroll
      for (int r = 0; r < 4; ++r) {
        const int key = f * 16 + quad * 4 + r;
        float v = c[f][r] * 0.125f;
        v = (key < 77) ? v : -1e30f;
        c[f][r] = v;
        mx = fmaxf(mx, v);
      }
    mx = fmaxf(mx, __shfl_xor(mx, 16));
    mx = fmaxf(mx, __shfl_xor(mx, 32));

    short* pbase = Pw + (w * 16 + l16) * 80;
    float sum = 0.f;
#pragma unroll
    for (int f = 0; f < 5; ++f) {
      float e0 = __expf(c[f][0] - mx), e1 = __expf(c[f][1] - mx);
      float e2 = __expf(c[f][2] - mx), e3 = __expf(c[f][3] - mx);
      sum += (e0 + e1) + (e2 + e3);
      uint2v sv2 = {pkbf(e0, e1), pkbf(e2, e3)};
      *(uint2v*)(pbase + f * 16 + quad * 4) = sv2;
    }
    sum += __shfl_xor(sum, 16);
    sum += __shfl_xor(sum, 32);
    const float inv = 1.0f / sum;

    bf16x8 pb0 = *(bf16x8*)(pbase + quad * 8);
    bf16x8 pb1 = *(bf16x8*)(pbase + 32 + quad * 8);
    bf16x8 pb2 = bf16x8{0, 0, 0, 0, 0, 0, 0, 0};
    if (quad < 2) pb2 = *(bf16x8*)(pbase + 64 + quad * 8);

    f32x4 o[4] = {};
#pragma unroll
    for (int mt = 0; mt < 4; ++mt) {
      const short* vrow = &Vt[wm * 6144 + (mt * 16 + l16) * 96];
      o[mt] = __builtin_amdgcn_mfma_f32_16x16x32_bf16(
          *(bf16x8*)(vrow + quad * 8), pb0, o[mt], 0, 0, 0);
      o[mt] = __builtin_amdgcn_mfma_f32_16x16x32_bf16(
          *(bf16x8*)(vrow + 32 + quad * 8), pb1, o[mt], 0, 0, 0);
      o[mt] = __builtin_amdgcn_mfma_f32_16x16x32_bf16(
          *(bf16x8*)(vrow + 64 + quad * 8), pb2, o[mt], 0, 0, 0);
    }

    short* op = AOb + ((size_t)m0 + wn * 16 + l16) * 512 + (it * 2 + wm) * 64;
#pragma unroll
    for (int mt = 0; mt < 4; ++mt) {
      uint2v sv2 = {pkbf(o[mt][0] * inv, o[mt][1] * inv),
                    pkbf(o[mt][2] * inv, o[mt][3] * inv)};
      *(uint2v*)(op + mt * 16 + quad * 4) = sv2;
    }
  }
}

// ---------------- O-proj: 2-phase dbuf GEMM, bf16 A/B (round-12 proven) ----
__global__ __launch_bounds__(256) void gemm2(const short* __restrict__ A,
                                             const short* __restrict__ Bt,
                                             float* __restrict__ C,
                                             const float* __restrict__ bias) {
  __shared__ short As[2][128 * 64];
  __shared__ short Bs[2][128 * 64];

  const int tid = threadIdx.x;
  const int lane = tid & 63, w = tid >> 6;
  const int wm = w >> 1, wn = w & 1;
  const int quad = lane >> 4, l16 = lane & 15;

  const int cpx = gridDim.x >> 3;
  const int swz = (blockIdx.x & 7) * cpx + (blockIdx.x >> 3);
  const int m0 = (swz >> 2) * 128, n0 = (swz & 3) * 128;

  const int lr = lane >> 3, lc = (lane & 7) * 8;

  f32x4 acc[4][4] = {};

#pragma unroll
  for (int p = 0; p < 4; ++p) {
    const int rowb = w * 32 + p * 8;
    GLDS16(A + (size_t)(m0 + rowb + lr) * 512 + lc, &As[0][rowb * 64]);
    GLDS16(Bt + (size_t)(n0 + rowb + lr) * 512 + lc, &Bs[0][rowb * 64]);
  }
  __syncthreads();

  for (int t = 0; t < 8; ++t) {
    const int cur = t & 1;
    if (t < 7) {
      const int k1 = (t + 1) * 64;
#pragma unroll
      for (int p = 0; p < 4; ++p) {
        const int rowb = w * 32 + p * 8;
        GLDS16(A + (size_t)(m0 + rowb + lr) * 512 + k1 + lc,
               &As[cur ^ 1][rowb * 64]);
        GLDS16(Bt + (size_t)(n0 + rowb + lr) * 512 + k1 + lc,
               &Bs[cur ^ 1][rowb * 64]);
      }
    }
#pragma unroll
    for (int ks = 0; ks < 2; ++ks) {
      bf16x8 af[4], bfr[4];
#pragma unroll
      for (int m = 0; m < 4; ++m)
        af[m] = *(bf16x8*)&As[cur][(wm * 64 + m * 16 + l16) * 64 + ks * 32 + quad * 8];
#pragma unroll
      for (int n = 0; n < 4; ++n)
        bfr[n] = *(bf16x8*)&Bs[cur][(wn * 64 + n * 16 + l16) * 64 + ks * 32 + quad * 8];
#pragma unroll
      for (int m = 0; m < 4; ++m)
#pragma unroll
        for (int n = 0; n < 4; ++n)
          acc[m][n] = __builtin_amdgcn_mfma_f32_16x16x32_bf16(af[m], bfr[n],
                                                              acc[m][n], 0, 0, 0);
    }
    if (t < 7) __syncthreads();
  }

#pragma unroll
  for (int m = 0; m < 4; ++m)
#pragma unroll
    for (int n = 0; n < 4; ++n) {
      const int col = n0 + wn * 64 + n * 16 + l16;
      const int rowb = m0 + wm * 64 + m * 16 + quad * 4;
      const float badd = bias[col];
#pragma unroll
      for (int r = 0; r < 4; ++r)
        C[(size_t)(rowb + r) * 512 + col] = acc[m][n][r] + badd;
    }
}

extern "C" void kernel_launch(void* const* d_in, const int* in_sizes, int n_in,
                              void* d_out, int out_size, void* d_ws, size_t ws_size,
                              hipStream_t stream) {
  const float* x   = (const float*)d_in[0];
  const float* ctx = (const float*)d_in[1];
  const float* Wq  = (const float*)d_in[2];
  const float* Wk  = (const float*)d_in[3];
  const float* Wv  = (const float*)d_in[4];
  const float* Wo  = (const float*)d_in[5];
  const float* bo  = (const float*)d_in[6];
  float* out = (float*)d_out;

  char* ws = (char*)d_ws;
  size_t off = 0;
  short* wqt = (short*)(ws + off); off += 512 * 512 * 2;
  short* wkt = (short*)(ws + off); off += 768 * 512 * 2;
  short* wvt = (short*)(ws + off); off += 768 * 512 * 2;
  short* wot = (short*)(ws + off); off += 512 * 512 * 2;
  short* Kb  = (short*)(ws + off); off += 1232 * 512 * 2;
  short* Vtg = (short*)(ws + off); off += (size_t)16 * 8 * 64 * 96 * 2;
  short* AOb = (short*)(ws + off); off += (size_t)65536 * 512 * 2;

  // all weight transposes + Vtg zero-fill in one dispatch
  prep_all<<<dim3(8, 12, 5), 256, 0, stream>>>(Wq, Wk, Wv, Wo,
                                               wqt, wkt, wvt, wot,
                                               (float4v*)Vtg);
  // K and V projections in one dispatch
  kvproj<<<dim3(4, 39, 2), 256, 0, stream>>>(ctx, wkt, wvt, Kb, Vtg);

  // fused Q-proj + attention -> AOb bf16
  qattn<<<512, 1024, 0, stream>>>(x, wqt, Kb, Vtg, AOb);

  // output projection + bias -> f32 d_out
  gemm2<<<2048, 256, 0, stream>>>(AOb, wot, out, bo);
}